// Round 5
// baseline (199.121 us; speedup 1.0000x reference)
//
#include <hip/hip_runtime.h>
#include <cstdint>
#include <cstddef>

#define DEV __device__ __forceinline__

typedef __bf16 bf16_t;
typedef __bf16 bf16x8 __attribute__((ext_vector_type(8)));
typedef float  f32x4  __attribute__((ext_vector_type(4)));
typedef float  f32x2  __attribute__((ext_vector_type(2)));
typedef unsigned int u32x4 __attribute__((ext_vector_type(4)));

DEV bf16_t f2bf(float x) { return (bf16_t)x; }   // RNE cast

// ---- problem sizes ----
constexpr int R_ = 500, C_ = 512, H_ = 38, W_ = 38, K_ = 20;
constexpr int HID = 4096, FEAT = 4608, MP = 512;  // MP = padded M
constexpr int HW = H_ * W_;                        // 1444

// ---- workspace layout ----
constexpr size_t alup(size_t x) { return (x + 255) & ~(size_t)255; }
constexpr size_t O_FMT  = 0;                                        // fmap transposed [1444][512] f32
constexpr size_t O_RSC  = alup(O_FMT  + (size_t)HW*C_*4);           // rois_sc [500][4] f32
constexpr size_t O_FEAT = alup(O_RSC  + (size_t)R_*4*4);            // feat bf16 [512][4608]
constexpr size_t O_FC6  = alup(O_FEAT + (size_t)MP*FEAT*2);         // fc6 bf16 [512][4096]
constexpr size_t O_FC7  = alup(O_FC6  + (size_t)MP*HID*2);          // fc7 f32 [512][4096]
constexpr size_t O_PC   = alup(O_FC7  + (size_t)MP*HID*4);          // pc [500][20] f32
constexpr size_t O_LD   = alup(O_PC   + (size_t)R_*K_*4);           // logits_d [500][20] f32
constexpr size_t O_AN   = alup(O_LD   + (size_t)R_*K_*4);           // ||fc7[r]||^2 [512] f32
constexpr size_t O_OS   = alup(O_AN   + (size_t)MP*4);              // out_sum [20]
constexpr size_t O_HI   = alup(O_OS   + (size_t)K_*4);              // h_idx [20] int
constexpr size_t O_D    = alup(O_HI   + (size_t)K_*4);              // D [500][20] f32
constexpr size_t O_W8T  = alup(O_D    + (size_t)R_*K_*4);           // W8T [40][4096] f32
constexpr size_t O_PART = alup(O_W8T  + (size_t)2*K_*HID*4);        // split-K partials (33.5 MB)
// heads/dmat partials alias the part region (part is dead by then)
constexpr size_t O_HP   = O_PART;                                   // [32][512][41] f32 (2.75 MB)
constexpr size_t O_DP   = O_PART + (size_t)4*1024*1024;             // [32][512][20] f32 (1.31 MB)

// ---- fmap transpose: [C][HW] -> [HW][C], tiled through LDS (both sides coalesced) ----
__global__ void __launch_bounds__(256) k_transpose(const float* __restrict__ fmap,
                                                   float* __restrict__ fmapt) {
    __shared__ float tile[32][33];
    int p0 = blockIdx.x * 32, c0 = blockIdx.y * 32;
    int tx = threadIdx.x & 31, ty = threadIdx.x >> 5;     // ty in 0..7
#pragma unroll
    for (int i = 0; i < 4; ++i) {
        int c = c0 + ty + i*8, p = p0 + tx;
        tile[ty + i*8][tx] = (p < HW) ? fmap[(size_t)c*HW + p] : 0.f;
    }
    __syncthreads();
#pragma unroll
    for (int i = 0; i < 4; ++i) {
        int p = p0 + ty + i*8, c = c0 + tx;
        if (p < HW) fmapt[(size_t)p*C_ + c] = tile[tx][ty + i*8];
    }
}

// ---- W8c/W8d transpose: [4096][20] -> W8T[40][4096] ----
__global__ void __launch_bounds__(256) k_w8t(const float* __restrict__ W8c,
                                             const float* __restrict__ W8d,
                                             float* __restrict__ W8T) {
    int k = blockIdx.x;                                   // 0..39
    const float* src = (k < K_) ? W8c : W8d;
    int kk = (k < K_) ? k : k - K_;
    for (int i = threadIdx.x; i < HID; i += 256)
        W8T[(size_t)k*HID + i] = src[(size_t)i*K_ + kk];
}

// ---- ROI max pool, split over (roi, bin): feat[r, c*9 + bin] ----
__global__ void __launch_bounds__(256) k_roipool(const float* __restrict__ fmapt,
                                                 const float* __restrict__ rois,
                                                 bf16_t* __restrict__ feat,
                                                 float* __restrict__ rois_sc) {
    int r = blockIdx.x, bin = blockIdx.y, t = threadIdx.x;
    if (r >= R_) {   // zero the M-padding rows so the GEMM sees zeros
        feat[(size_t)r*FEAT + (size_t)t*9       + bin] = (bf16_t)0.f;
        feat[(size_t)r*FEAT + (size_t)(t+256)*9 + bin] = (bf16_t)0.f;
        return;
    }
    int x1 = (int)floorf(rois[r*4+0] * 0.0625f);
    int y1 = (int)floorf(rois[r*4+1] * 0.0625f);
    int x2 = (int)floorf(rois[r*4+2] * 0.0625f);
    int y2 = (int)floorf(rois[r*4+3] * 0.0625f);
    if (bin == 0 && t == 0) {
        rois_sc[r*4+0] = (float)x1; rois_sc[r*4+1] = (float)y1;
        rois_sc[r*4+2] = (float)x2; rois_sc[r*4+3] = (float)y2;
    }
    int Lx = x2 - x1, Ly = y2 - y1;
    int pr = bin / 3, px = bin - pr*3;
    int rs = y1 + (pr*Ly)/3, re = y1 + ((pr+1)*Ly + 2)/3;
    int cs = x1 + (px*Lx)/3, ce = x1 + ((px+1)*Lx + 2)/3;
    float m0 = -3.402823466e38f, m1 = -3.402823466e38f;
    for (int y = rs; y < re; ++y) {
        const float* rowp = fmapt + (size_t)(y*W_)*C_;
        for (int x = cs; x < ce; ++x) {
            const float* p = rowp + (size_t)x*C_;
            m0 = fmaxf(m0, p[t]);
            m1 = fmaxf(m1, p[t + 256]);
        }
    }
    feat[(size_t)r*FEAT + (size_t)t*9       + bin] = f2bf(m0);
    feat[(size_t)r*FEAT + (size_t)(t+256)*9 + bin] = f2bf(m1);
}

// ---- bf16 MFMA GEMM: part[bz] = A[512xK](bf16) * B[Kx4096](f32 -> bf16) ----
// BM=128, BN=64, BK=64, 4 waves (64x32 each), double-buffered XOR-swizzled LDS
// (48 KB -> 3 blocks/CU), one barrier per K-step (round-2 schedule).
// A staged via global_load_lds (16B) with pre-swizzled per-lane SOURCE addrs;
// B reg-staged as coalesced f32x2, cast to bf16, written transposed [n][k]
// with the same 16B-slot XOR swizzle (r4-verified: 0 bank conflicts).
__global__ void __launch_bounds__(256, 3)
k_gemm(const bf16_t* __restrict__ A, const float* __restrict__ B,
       float* __restrict__ part, int KDIM, int nts) {
    __shared__ bf16_t Asm[2][128*64];   // 16 KB per buffer
    __shared__ bf16_t Bsm[2][64*64];    // 8 KB per buffer, [n][k] swizzled
    const int t = threadIdx.x;
    const int lane = t & 63, wid = t >> 6;
    const int wr = wid >> 1, wc = wid & 1;

    // XCD-aware bijective decode: grid (64,4,4)=1024; by fastest within a chunk
    // so the 4 M-tiles sharing a B panel are temporally adjacent on one XCD.
    const int flat = blockIdx.x + 64*blockIdx.y + 256*blockIdx.z;   // 0..1023
    const int v = (flat & 7) * 128 + (flat >> 3);
    const int by = v & 3, bx = (v >> 2) & 63, bz = v >> 8;

    const int brow = by * 128, bcol = bx * 64;
    const int kt0 = bz * nts;

    f32x4 acc[4][2] = {};
    f32x2 br[8];
    const int n2 = t & 31, kgl = t >> 5;      // B: cols {2n2, 2n2+1}, k-octet kgl

    auto stage_A = [&](int kt, int buf) {     // async global->LDS, swizzled source
        const bf16_t* Ag = A + (size_t)brow*KDIM + kt*64;
#pragma unroll
        for (int i = 0; i < 4; ++i) {
            int s = t + i*256;                          // LDS 16B-slot (linear dest)
            int row = s >> 3;
            int kb = (s & 7) ^ ((row >> 1) & 7);        // pre-swizzled source octet
            const bf16_t* src = Ag + (size_t)row*KDIM + kb*8;
            bf16_t* dst = &Asm[buf][(size_t)(i*256 + (t & ~63)) * 8];  // wave-uniform base
            __builtin_amdgcn_global_load_lds(
                (const __attribute__((address_space(1))) void*)src,
                (__attribute__((address_space(3))) void*)dst, 16, 0, 0);
        }
    };
    auto load_B = [&](int kt) {
        const float* src = B + (size_t)(kt*64 + kgl*8)*HID + bcol + 2*n2;
#pragma unroll
        for (int j = 0; j < 8; ++j)                     // wave-coalesced rows
            br[j] = *reinterpret_cast<const f32x2*>(src + (size_t)j*HID);
    };
    auto write_B = [&](int buf) {
        const int sw = n2 & 7;                          // (col>>1)&7, same for both cols
        bf16x8 v0, v1;
#pragma unroll
        for (int j = 0; j < 8; ++j) { v0[j] = f2bf(br[j].x); v1[j] = f2bf(br[j].y); }
        *reinterpret_cast<u32x4*>(&Bsm[buf][(size_t)((2*n2    )*8 + (kgl ^ sw)) * 8]) = *reinterpret_cast<u32x4*>(&v0);
        *reinterpret_cast<u32x4*>(&Bsm[buf][(size_t)((2*n2 + 1)*8 + (kgl ^ sw)) * 8]) = *reinterpret_cast<u32x4*>(&v1);
    };

    stage_A(kt0, 0);
    load_B(kt0);
    write_B(0);
    __syncthreads();                                    // drains load_lds too

    for (int it = 0; it < nts; ++it) {
        const int cur = it & 1;
        if (it + 1 < nts) { stage_A(kt0 + it + 1, cur ^ 1); load_B(kt0 + it + 1); }
#pragma unroll
        for (int kk = 0; kk < 2; ++kk) {
            const int kb = kk*4 + (lane >> 4);
            bf16x8 af[4], bfr[2];
#pragma unroll
            for (int m = 0; m < 4; ++m) {
                int row = wr*64 + m*16 + (lane & 15);
                af[m] = *reinterpret_cast<const bf16x8*>(
                    &Asm[cur][(size_t)(row*8 + (kb ^ ((row >> 1) & 7))) * 8]);
            }
#pragma unroll
            for (int n = 0; n < 2; ++n) {
                int nn = wc*32 + n*16 + (lane & 15);
                bfr[n] = *reinterpret_cast<const bf16x8*>(
                    &Bsm[cur][(size_t)(nn*8 + (kb ^ ((nn >> 1) & 7))) * 8]);
            }
#pragma unroll
            for (int m = 0; m < 4; ++m)
#pragma unroll
                for (int n = 0; n < 2; ++n)
                    acc[m][n] = __builtin_amdgcn_mfma_f32_16x16x32_bf16(af[m], bfr[n], acc[m][n], 0, 0, 0);
        }
        if (it + 1 < nts) { write_B(cur ^ 1); __syncthreads(); }
    }

    float* dst = part + (size_t)bz * MP * HID;
#pragma unroll
    for (int m = 0; m < 4; ++m) {
        int row0 = brow + wr*64 + m*16 + ((lane >> 4) << 2);
#pragma unroll
        for (int n = 0; n < 2; ++n) {
            int col = bcol + wc*32 + n*16 + (lane & 15);
#pragma unroll
            for (int j = 0; j < 4; ++j)
                dst[(size_t)(row0 + j)*HID + col] = acc[m][n][j];
        }
    }
}

// ---- split-K reduce + bias; writes bf16 (fc6) or f32 (fc7) ----
__global__ void __launch_bounds__(256) k_reduce(const float* __restrict__ part,
                                                const float* __restrict__ bias,
                                                bf16_t* __restrict__ ob, float* __restrict__ of,
                                                int ksplit) {
    size_t idx = ((size_t)blockIdx.x*256 + threadIdx.x) * 4;
    f32x4 s = *reinterpret_cast<const f32x4*>(part + idx);
    for (int ss = 1; ss < ksplit; ++ss)
        s += *reinterpret_cast<const f32x4*>(part + (size_t)ss*MP*HID + idx);
    int col = (int)(idx & (HID - 1));
    s += *reinterpret_cast<const f32x4*>(bias + col);
    if (ob) {
#pragma unroll
        for (int j = 0; j < 4; ++j) ob[idx + j] = f2bf(s[j]);
    } else {
        *reinterpret_cast<f32x4*>(of + idx) = s;
    }
}

// ---- tiled column-dots: partial[kb][r][o] = fc7[r][kchunk] . Brow_o[kchunk] ----
// Brow_o = Bmat[o] (heads: W8T, 40 rows) or fc7[bidx[o]] (dmat gather).
// SELF adds output NOUT = ||fc7[r][kchunk]||^2 (for An).
// grid (MP/64, HID/128); 4 waves; lane = (ri: 8 row-pairs, kk: 8 k-slices of 16).
template<int NOUT, bool SELF>
__global__ void __launch_bounds__(256) k_dotcols(const float* __restrict__ fc7,
        const float* __restrict__ Bmat, const int* __restrict__ bidx,
        float* __restrict__ partial) {
    constexpr int NO = NOUT + (SELF ? 1 : 0);
    constexpr int SLICE = NOUT*16 + 4;       // word stride per kk-slice: = 4 mod 32 -> 8 bank-quads
    __shared__ float Bs[8 * SLICE];
    const int rb = blockIdx.x, kb = blockIdx.y, t = threadIdx.x;
    const int k0 = kb * 128;
    for (int i = t; i < NOUT*32; i += 256) {             // stage Bmat chunk (f32x4 units)
        int o = i >> 5, c = i & 31;                      // c = k/4 within chunk
        const float* src = bidx ? fc7 + (size_t)bidx[o]*HID : Bmat + (size_t)o*HID;
        f32x4 v = *reinterpret_cast<const f32x4*>(src + k0 + c*4);
        *reinterpret_cast<f32x4*>(&Bs[(c >> 2)*SLICE + o*16 + (c & 3)*4]) = v;
    }
    __syncthreads();
    const int lane = t & 63, w = t >> 6;
    const int ri = lane >> 3, kk = lane & 7;
    const int r0 = rb*64 + w*16 + ri*2;                  // two rows per lane
    f32x4 x0[4], x1[4];
    const float* f0 = fc7 + (size_t)r0*HID + k0 + kk*16;
#pragma unroll
    for (int j = 0; j < 4; ++j) {
        x0[j] = *reinterpret_cast<const f32x4*>(f0 + j*4);
        x1[j] = *reinterpret_cast<const f32x4*>(f0 + HID + j*4);
    }
    float acc0[NO], acc1[NO];
#pragma unroll
    for (int o = 0; o < NOUT; ++o) {
        f32x4 s0 = {}, s1 = {};
#pragma unroll
        for (int j = 0; j < 4; ++j) {
            f32x4 wv = *reinterpret_cast<const f32x4*>(&Bs[kk*SLICE + o*16 + j*4]);
            s0 += x0[j] * wv;
            s1 += x1[j] * wv;
        }
        acc0[o] = s0[0]+s0[1]+s0[2]+s0[3];
        acc1[o] = s1[0]+s1[1]+s1[2]+s1[3];
    }
    if (SELF) {
        f32x4 s0 = {}, s1 = {};
#pragma unroll
        for (int j = 0; j < 4; ++j) { s0 += x0[j]*x0[j]; s1 += x1[j]*x1[j]; }
        acc0[NO-1] = s0[0]+s0[1]+s0[2]+s0[3];
        acc1[NO-1] = s1[0]+s1[1]+s1[2]+s1[3];
    }
#pragma unroll
    for (int o = 0; o < NO; ++o) {
#pragma unroll
        for (int m = 1; m < 8; m <<= 1) {
            acc0[o] += __shfl_xor(acc0[o], m, 64);
            acc1[o] += __shfl_xor(acc1[o], m, 64);
        }
    }
    if (kk == 0) {
#pragma unroll
        for (int o = 0; o < NO; ++o) {
            partial[((size_t)kb*MP + r0    )*NO + o] = acc0[o];
            partial[((size_t)kb*MP + r0 + 1)*NO + o] = acc1[o];
        }
    }
}

// ---- heads reduce: sum 32 k-chunk partials, add bias, row softmax -> pc; ld; An ----
__global__ void __launch_bounds__(64) k_headred(const float* __restrict__ hpart,
        const float* __restrict__ b8c, const float* __restrict__ b8d,
        float* __restrict__ pc, float* __restrict__ ld, float* __restrict__ An) {
    int r = blockIdx.x, t = threadIdx.x;
    __shared__ float lcs[20];
    if (t < 41) {
        float s = 0.f;
        for (int kb = 0; kb < 32; ++kb) s += hpart[((size_t)kb*MP + r)*41 + t];
        if (t < 20)      lcs[t] = s + b8c[t];
        else if (t < 40) ld[r*K_ + (t-20)] = s + b8d[t-20];
        else             An[r] = s;
    }
    __syncthreads();
    if (t == 0) {
        float mx = lcs[0];
#pragma unroll
        for (int k = 1; k < 20; ++k) mx = fmaxf(mx, lcs[k]);
        float sum = 0.f, e[20];
#pragma unroll
        for (int k = 0; k < 20; ++k) { e[k] = expf(lcs[k] - mx); sum += e[k]; }
        float inv = 1.f / sum;
#pragma unroll
        for (int k = 0; k < 20; ++k) pc[r*K_ + k] = e[k] * inv;
    }
}

// ---- dmat reduce: D[r][k] = sum of 32 partials ----
__global__ void __launch_bounds__(64) k_dmatred(const float* __restrict__ dpart,
                                                float* __restrict__ D) {
    int r = blockIdx.x, t = threadIdx.x;
    if (t < 20) {
        float s = 0.f;
        for (int kb = 0; kb < 32; ++kb) s += dpart[((size_t)kb*MP + r)*20 + t];
        D[r*K_ + t] = s;
    }
}

// ---- per-class column softmax, scores, column sum, argmin (stable) ----
__global__ void __launch_bounds__(256) k_pd(const float* __restrict__ ld,
        const float* __restrict__ pc, float* __restrict__ scores,
        float* __restrict__ out_sum, int* __restrict__ h_idx) {
    int k = blockIdx.x, t = threadIdx.x;
    __shared__ float sh[4];
    float m = -3.402823466e38f;
    for (int r = t; r < R_; r += 256) m = fmaxf(m, ld[r*K_ + k]);
    for (int off = 1; off < 64; off <<= 1) m = fmaxf(m, __shfl_xor(m, off, 64));
    if ((t & 63) == 0) sh[t >> 6] = m;
    __syncthreads();
    m = fmaxf(fmaxf(sh[0], sh[1]), fmaxf(sh[2], sh[3]));
    __syncthreads();
    float s = 0.f;
    for (int r = t; r < R_; r += 256) s += expf(ld[r*K_ + k] - m);
    for (int off = 1; off < 64; off <<= 1) s += __shfl_xor(s, off, 64);
    if ((t & 63) == 0) sh[t >> 6] = s;
    __syncthreads();
    s = sh[0] + sh[1] + sh[2] + sh[3];
    float inv = 1.f / s;

    float osum = 0.f, bv = 3.402823466e38f; int bi = 0x7fffffff;
    for (int r = t; r < R_; r += 256) {
        float p  = expf(ld[r*K_ + k] - m) * inv;
        float sc = pc[r*K_ + k] * p;
        scores[r*K_ + k] = sc;
        osum += sc;
        if (sc < bv || (sc == bv && r < bi)) { bv = sc; bi = r; }
    }
    for (int off = 1; off < 64; off <<= 1) osum += __shfl_xor(osum, off, 64);
    for (int off = 1; off < 64; off <<= 1) {
        float v2 = __shfl_xor(bv, off, 64);
        int   i2 = __shfl_xor(bi, off, 64);
        if (v2 < bv || (v2 == bv && i2 < bi)) { bv = v2; bi = i2; }
    }
    __shared__ float so[4], mv[4]; __shared__ int mi[4];
    if ((t & 63) == 0) { so[t >> 6] = osum; mv[t >> 6] = bv; mi[t >> 6] = bi; }
    __syncthreads();
    if (t == 0) {
        out_sum[k] = so[0] + so[1] + so[2] + so[3];
        float v = mv[0]; int i = mi[0];
        for (int w = 1; w < 4; ++w)
            if (mv[w] < v || (mv[w] == v && mi[w] < i)) { v = mv[w]; i = mi[w]; }
        h_idx[k] = i;
    }
}

// ---- final: BCE + spatial regularizer ----
__global__ void __launch_bounds__(256) k_final(const float* __restrict__ out_sum,
        const int* __restrict__ h_idx, const float* __restrict__ label,
        const float* __restrict__ scores, const float* __restrict__ D,
        const float* __restrict__ An, const float* __restrict__ rois_sc,
        float* __restrict__ dout) {
    int t = threadIdx.x;
    __shared__ float bsh[20];
    if (t < 20) {
        float o = out_sum[t], lab = label[t];
        bsh[t] = lab * logf(o) + (1.f - lab) * logf(1.f - o);
    }
    __syncthreads();

    float rp = 0.f;
    for (int i = t; i < R_*K_; i += 256) {
        int r = i / 20, k = i - r*20;
        int h = h_idx[k];
        if (r == h) continue;
        float lab = label[k];
        if (lab == 0.f) continue;
        float s = scores[r*K_ + k];
        const float* rb = rois_sc + r*4;
        const float* hb = rois_sc + h*4;
        float b1x2 = rb[0] + rb[2], b1y2 = rb[1] + rb[3];
        float b2x2 = hb[0] + hb[2], b2y2 = hb[1] + hb[3];
        float iw = fmaxf(fminf(b1x2, b2x2) - fmaxf(rb[0], hb[0]) + 1.f, 0.f);
        float ih = fmaxf(fminf(b1y2, b2y2) - fmaxf(rb[1], hb[1]) + 1.f, 0.f);
        float inter = iw * ih;
        float a1 = (b1x2 - rb[0] + 1.f) * (b1y2 - rb[1] + 1.f);
        float a2 = (b2x2 - hb[0] + 1.f) * (b2y2 - hb[1] + 1.f);
        float iou = inter / (a1 + a2 - inter);
        float mm = (iou > 0.6f) ? 1.f : 0.f;
        float term = mm * (An[r] - 2.f * D[r*K_ + k]) + An[h];
        rp += lab * 0.5f * s * s * term;
    }
    for (int off = 1; off < 64; off <<= 1) rp += __shfl_xor(rp, off, 64);
    __shared__ float rsh[4];
    if ((t & 63) == 0) rsh[t >> 6] = rp;
    __syncthreads();
    if (t == 0) {
        float reg = (rsh[0] + rsh[1] + rsh[2] + rsh[3]) / (float)K_;
        float b = 0.f;
        for (int k = 0; k < 20; ++k) b += bsh[k];
        float bce = -b / (float)K_;
        dout[R_*K_]     = bce + reg;
        dout[R_*K_ + 1] = reg;
    }
}

extern "C" void kernel_launch(void* const* d_in, const int* in_sizes, int n_in,
                              void* d_out, int out_size, void* d_ws, size_t ws_size,
                              hipStream_t stream) {
    const float* fmap  = (const float*)d_in[0];
    const float* rois  = (const float*)d_in[1];
    const float* label = (const float*)d_in[2];
    const float* W6    = (const float*)d_in[3];
    const float* b6    = (const float*)d_in[4];
    const float* W7    = (const float*)d_in[5];
    const float* b7    = (const float*)d_in[6];
    const float* W8c   = (const float*)d_in[7];
    const float* b8c   = (const float*)d_in[8];
    const float* W8d   = (const float*)d_in[9];
    const float* b8d   = (const float*)d_in[10];
    char* ws = (char*)d_ws;
    float* out = (float*)d_out;

    float*  fmapt = (float*)(ws + O_FMT);
    float*  roisc = (float*)(ws + O_RSC);
    bf16_t* feat  = (bf16_t*)(ws + O_FEAT);
    bf16_t* fc6   = (bf16_t*)(ws + O_FC6);
    float*  fc7   = (float*)(ws + O_FC7);
    float*  pc    = (float*)(ws + O_PC);
    float*  ld    = (float*)(ws + O_LD);
    float*  An    = (float*)(ws + O_AN);
    float*  osum  = (float*)(ws + O_OS);
    int*    hidx  = (int*)(ws + O_HI);
    float*  Dm    = (float*)(ws + O_D);
    float*  w8t   = (float*)(ws + O_W8T);
    float*  part  = (float*)(ws + O_PART);
    float*  hpart = (float*)(ws + O_HP);
    float*  dpart = (float*)(ws + O_DP);

    const int ksplit = 4;

    k_transpose<<<dim3((HW + 31)/32, C_/32), dim3(256), 0, stream>>>(fmap, fmapt);
    k_w8t      <<<dim3(2*K_),   dim3(256), 0, stream>>>(W8c, W8d, w8t);
    k_roipool  <<<dim3(MP, 9),  dim3(256), 0, stream>>>(fmapt, rois, feat, roisc);

    k_gemm  <<<dim3(HID/64, MP/128, ksplit), dim3(256), 0, stream>>>(feat, W6, part, FEAT, (FEAT/64)/ksplit);
    k_reduce<<<dim3((MP*HID)/1024), dim3(256), 0, stream>>>(part, b6, fc6, (float*)nullptr, ksplit);

    k_gemm  <<<dim3(HID/64, MP/128, ksplit), dim3(256), 0, stream>>>(fc6, W7, part, HID, (HID/64)/ksplit);
    k_reduce<<<dim3((MP*HID)/1024), dim3(256), 0, stream>>>(part, b7, (bf16_t*)nullptr, fc7, ksplit);

    k_dotcols<40, true><<<dim3(MP/64, HID/128), dim3(256), 0, stream>>>(fc7, w8t, (const int*)nullptr, hpart);
    k_headred<<<dim3(R_), dim3(64), 0, stream>>>(hpart, b8c, b8d, pc, ld, An);
    k_pd     <<<dim3(K_), dim3(256), 0, stream>>>(ld, pc, out, osum, hidx);
    k_dotcols<20, false><<<dim3(MP/64, HID/128), dim3(256), 0, stream>>>(fc7, (const float*)nullptr, hidx, dpart);
    k_dmatred<<<dim3(R_), dim3(64), 0, stream>>>(dpart, Dm);
    k_final  <<<dim3(1),  dim3(256), 0, stream>>>(osum, hidx, label, out, Dm, An, roisc, out);
}

// Round 6
// 178.537 us; speedup vs baseline: 1.1153x; 1.1153x over previous
//
#include <hip/hip_runtime.h>
#include <cstdint>
#include <cstddef>

#define DEV __device__ __forceinline__

typedef __bf16 bf16_t;
typedef __bf16 bf16x8 __attribute__((ext_vector_type(8)));
typedef float  f32x4  __attribute__((ext_vector_type(4)));
typedef float  f32x2  __attribute__((ext_vector_type(2)));
typedef unsigned int u32x4 __attribute__((ext_vector_type(4)));

DEV bf16_t f2bf(float x) { return (bf16_t)x; }   // RNE cast

// ---- problem sizes ----
constexpr int R_ = 500, C_ = 512, H_ = 38, W_ = 38, K_ = 20;
constexpr int HID = 4096, FEAT = 4608, MP = 512;  // MP = padded M
constexpr int HW = H_ * W_;                        // 1444

// ---- workspace layout ----
constexpr size_t alup(size_t x) { return (x + 255) & ~(size_t)255; }
constexpr size_t O_FMT  = 0;                                        // fmap transposed [1444][512] f32
constexpr size_t O_RSC  = alup(O_FMT  + (size_t)HW*C_*4);           // rois_sc [500][4] f32
constexpr size_t O_FEAT = alup(O_RSC  + (size_t)R_*4*4);            // feat bf16 [512][4608]
constexpr size_t O_FC6  = alup(O_FEAT + (size_t)MP*FEAT*2);         // fc6 bf16 [512][4096]
constexpr size_t O_FC7  = alup(O_FC6  + (size_t)MP*HID*2);          // fc7 f32 [512][4096]
constexpr size_t O_PC   = alup(O_FC7  + (size_t)MP*HID*4);          // pc [500][20] f32
constexpr size_t O_LD   = alup(O_PC   + (size_t)R_*K_*4);           // logits_d [500][20] f32
constexpr size_t O_AN   = alup(O_LD   + (size_t)R_*K_*4);           // ||fc7[r]||^2 [512] f32
constexpr size_t O_OS   = alup(O_AN   + (size_t)MP*4);              // out_sum [20]
constexpr size_t O_HI   = alup(O_OS   + (size_t)K_*4);              // h_idx [20] int
constexpr size_t O_D    = alup(O_HI   + (size_t)K_*4);              // D [500][20] f32
constexpr size_t O_W8T  = alup(O_D    + (size_t)R_*K_*4);           // W8T [40][4096] f32
constexpr size_t O_PART = alup(O_W8T  + (size_t)2*K_*HID*4);        // split-K partials (33.5 MB)
// heads/dmat partials alias the part region (part is dead by then)
constexpr size_t O_HP   = O_PART;                                   // [32][512][41] f32 (2.75 MB)
constexpr size_t O_DP   = O_PART + (size_t)4*1024*1024;             // [32][512][20] f32 (1.31 MB)

// ---- fmap transpose: [C][HW] -> [HW][C], tiled through LDS (both sides coalesced) ----
__global__ void __launch_bounds__(256) k_transpose(const float* __restrict__ fmap,
                                                   float* __restrict__ fmapt) {
    __shared__ float tile[32][33];
    int p0 = blockIdx.x * 32, c0 = blockIdx.y * 32;
    int tx = threadIdx.x & 31, ty = threadIdx.x >> 5;     // ty in 0..7
#pragma unroll
    for (int i = 0; i < 4; ++i) {
        int c = c0 + ty + i*8, p = p0 + tx;
        tile[ty + i*8][tx] = (p < HW) ? fmap[(size_t)c*HW + p] : 0.f;
    }
    __syncthreads();
#pragma unroll
    for (int i = 0; i < 4; ++i) {
        int p = p0 + ty + i*8, c = c0 + tx;
        if (p < HW) fmapt[(size_t)p*C_ + c] = tile[tx][ty + i*8];
    }
}

// ---- W8c/W8d transpose: [4096][20] -> W8T[40][4096] ----
__global__ void __launch_bounds__(256) k_w8t(const float* __restrict__ W8c,
                                             const float* __restrict__ W8d,
                                             float* __restrict__ W8T) {
    int k = blockIdx.x;                                   // 0..39
    const float* src = (k < K_) ? W8c : W8d;
    int kk = (k < K_) ? k : k - K_;
    for (int i = threadIdx.x; i < HID; i += 256)
        W8T[(size_t)k*HID + i] = src[(size_t)i*K_ + kk];
}

// ---- ROI max pool, split over (roi, bin): feat[r, c*9 + bin] ----
__global__ void __launch_bounds__(256) k_roipool(const float* __restrict__ fmapt,
                                                 const float* __restrict__ rois,
                                                 bf16_t* __restrict__ feat,
                                                 float* __restrict__ rois_sc) {
    int r = blockIdx.x, bin = blockIdx.y, t = threadIdx.x;
    if (r >= R_) {   // zero the M-padding rows so the GEMM sees zeros
        feat[(size_t)r*FEAT + (size_t)t*9       + bin] = (bf16_t)0.f;
        feat[(size_t)r*FEAT + (size_t)(t+256)*9 + bin] = (bf16_t)0.f;
        return;
    }
    int x1 = (int)floorf(rois[r*4+0] * 0.0625f);
    int y1 = (int)floorf(rois[r*4+1] * 0.0625f);
    int x2 = (int)floorf(rois[r*4+2] * 0.0625f);
    int y2 = (int)floorf(rois[r*4+3] * 0.0625f);
    if (bin == 0 && t == 0) {
        rois_sc[r*4+0] = (float)x1; rois_sc[r*4+1] = (float)y1;
        rois_sc[r*4+2] = (float)x2; rois_sc[r*4+3] = (float)y2;
    }
    int Lx = x2 - x1, Ly = y2 - y1;
    int pr = bin / 3, px = bin - pr*3;
    int rs = y1 + (pr*Ly)/3, re = y1 + ((pr+1)*Ly + 2)/3;
    int cs = x1 + (px*Lx)/3, ce = x1 + ((px+1)*Lx + 2)/3;
    float m0 = -3.402823466e38f, m1 = -3.402823466e38f;
    for (int y = rs; y < re; ++y) {
        const float* rowp = fmapt + (size_t)(y*W_)*C_;
        for (int x = cs; x < ce; ++x) {
            const float* p = rowp + (size_t)x*C_;
            m0 = fmaxf(m0, p[t]);
            m1 = fmaxf(m1, p[t + 256]);
        }
    }
    feat[(size_t)r*FEAT + (size_t)t*9       + bin] = f2bf(m0);
    feat[(size_t)r*FEAT + (size_t)(t+256)*9 + bin] = f2bf(m1);
}

// ---- bf16 MFMA GEMM: part[bz] = A[512xK](bf16) * B[Kx4096](f32 -> bf16) ----
// BM=BN=128, BK=64, 4 waves (64x64 each). Depth-2 software pipeline:
//   A: triple-buffered LDS, global_load_lds issued 2 iterations ahead
//   B: loads for t+2 issued at top of iter t into alternating reg sets;
//      write_B(t+1) after compute(t) -- the only forced wait is the
//      compiler's COUNTED vmcnt for 1-iteration-old B regs (12 newer ops
//      stay in flight). Raw s_barrier (no vmcnt(0) drain) + lgkmcnt(0).
// XOR-swizzled LDS (r4-verified: 0 bank conflicts). 80 KB -> 2 blocks/CU.
__global__ void __launch_bounds__(256, 2)
k_gemm(const bf16_t* __restrict__ A, const float* __restrict__ B,
       float* __restrict__ part, int KDIM, int nts) {
    __shared__ bf16_t Asm[3][128*64];   // 16 KB each (triple)
    __shared__ bf16_t Bsm[2][128*64];   // 16 KB each, [n][k] swizzled (double)
    const int t = threadIdx.x;
    const int lane = t & 63, wid = t >> 6;
    const int wr = wid >> 1, wc = wid & 1;

    // XCD-aware bijective decode: grid (32,4,4); by fastest within a chunk so
    // the 4 M-tiles sharing a B panel are temporally adjacent on one XCD.
    const int flat = blockIdx.x + 32*blockIdx.y + 128*blockIdx.z;
    const int q = 16 * gridDim.z;                       // nwg/8
    const int v = (flat & 7) * q + (flat >> 3);
    const int by = v & 3, bx = (v >> 2) & 31, bz = v >> 7;

    const int brow = by * 128, bcol = bx * 128;
    const int kt0 = bz * nts;

    f32x4 acc[4][4] = {};
    const int n2 = t & 63, kgl = t >> 6;      // B: cols {2n2,2n2+1}, k-stripe kgl*16

    auto stage_A = [&](int kt, bf16_t* dstbuf) {   // async global->LDS, swizzled src
        const bf16_t* Ag = A + (size_t)brow*KDIM + kt*64;
#pragma unroll
        for (int i = 0; i < 4; ++i) {
            int s = t + i*256;                          // LDS 16B-slot (linear dest)
            int row = s >> 3;
            int kb = (s & 7) ^ ((row >> 1) & 7);        // pre-swizzled source octet
            const bf16_t* src = Ag + (size_t)row*KDIM + kb*8;
            bf16_t* dst = dstbuf + (size_t)(i*256 + (t & ~63)) * 8;  // wave-uniform base
            __builtin_amdgcn_global_load_lds(
                (const __attribute__((address_space(1))) void*)src,
                (__attribute__((address_space(3))) void*)dst, 16, 0, 0);
        }
    };
    auto load_B = [&](int kt, f32x2* br) {
        const float* src = B + (size_t)(kt*64 + kgl*16)*HID + bcol + 2*n2;
#pragma unroll
        for (int j = 0; j < 16; ++j)                    // wave-coalesced 512B rows
            br[j] = *reinterpret_cast<const f32x2*>(src + (size_t)j*HID);
    };
    auto write_B = [&](f32x2* br, bf16_t* buf) {
        const int sw = n2 & 7;                          // (col>>1)&7, same for both cols
        bf16x8 v0, v1;
#pragma unroll
        for (int j = 0; j < 8; ++j) { v0[j] = f2bf(br[j].x); v1[j] = f2bf(br[j+8].x); }
        *reinterpret_cast<u32x4*>(&buf[(size_t)((2*n2)*8 + ((kgl*2    ) ^ sw)) * 8]) = *reinterpret_cast<u32x4*>(&v0);
        *reinterpret_cast<u32x4*>(&buf[(size_t)((2*n2)*8 + ((kgl*2 + 1) ^ sw)) * 8]) = *reinterpret_cast<u32x4*>(&v1);
#pragma unroll
        for (int j = 0; j < 8; ++j) { v0[j] = f2bf(br[j].y); v1[j] = f2bf(br[j+8].y); }
        *reinterpret_cast<u32x4*>(&buf[(size_t)((2*n2+1)*8 + ((kgl*2    ) ^ sw)) * 8]) = *reinterpret_cast<u32x4*>(&v0);
        *reinterpret_cast<u32x4*>(&buf[(size_t)((2*n2+1)*8 + ((kgl*2 + 1) ^ sw)) * 8]) = *reinterpret_cast<u32x4*>(&v1);
    };

    bf16_t* pa0 = &Asm[0][0]; bf16_t* pa1 = &Asm[1][0]; bf16_t* pa2 = &Asm[2][0];
    bf16_t* pb0 = &Bsm[0][0]; bf16_t* pb1 = &Bsm[1][0];
    f32x2 brA[16], brB[16];

    // prologue: stage A(0),A(1); load B(0),B(1); commit B(0) to LDS
    stage_A(kt0 + 0, pa0);
    load_B (kt0 + 0, brA);
    stage_A(kt0 + 1, pa1);
    load_B (kt0 + 1, brB);
    write_B(brA, pb0);                 // compiler inserts counted vmcnt for brA
    asm volatile("s_waitcnt lgkmcnt(0)" ::: "memory");
    __builtin_amdgcn_s_barrier();
    __builtin_amdgcn_sched_barrier(0);

    auto body = [&](int tt, f32x2* prev, f32x2* next) {
        if (tt + 2 < nts) { stage_A(kt0 + tt + 2, pa2); load_B(kt0 + tt + 2, next); }
#pragma unroll
        for (int kk = 0; kk < 2; ++kk) {
            const int kb = kk*4 + (lane >> 4);
            bf16x8 af[4], bfr[4];
#pragma unroll
            for (int m = 0; m < 4; ++m) {
                int row = wr*64 + m*16 + (lane & 15);
                af[m] = *reinterpret_cast<const bf16x8*>(
                    pa0 + (size_t)(row*8 + (kb ^ ((row >> 1) & 7))) * 8);
            }
#pragma unroll
            for (int n = 0; n < 4; ++n) {
                int nn = wc*64 + n*16 + (lane & 15);
                bfr[n] = *reinterpret_cast<const bf16x8*>(
                    pb0 + (size_t)(nn*8 + (kb ^ ((nn >> 1) & 7))) * 8);
            }
#pragma unroll
            for (int m = 0; m < 4; ++m)
#pragma unroll
                for (int n = 0; n < 4; ++n)
                    acc[m][n] = __builtin_amdgcn_mfma_f32_16x16x32_bf16(af[m], bfr[n], acc[m][n], 0, 0, 0);
        }
        if (tt + 1 < nts) {
            write_B(prev, pb1);        // B(t+1) into the other buffer; counted vmcnt
            asm volatile("s_waitcnt lgkmcnt(0)" ::: "memory");
            __builtin_amdgcn_s_barrier();
            __builtin_amdgcn_sched_barrier(0);
        }
        bf16_t* ta = pa0; pa0 = pa1; pa1 = pa2; pa2 = ta;   // rotate A triple-buffer
        bf16_t* tb = pb0; pb0 = pb1; pb1 = tb;              // swap B double-buffer
    };

    for (int it = 0; it < nts; it += 2) {      // nts is even (18 or 16)
        body(it,     brB, brA);                // prev holds B(it+1)
        body(it + 1, brA, brB);
    }

    float* dst = part + (size_t)bz * MP * HID;
#pragma unroll
    for (int m = 0; m < 4; ++m) {
        int row0 = brow + wr*64 + m*16 + ((lane >> 4) << 2);
#pragma unroll
        for (int n = 0; n < 4; ++n) {
            int col = bcol + wc*64 + n*16 + (lane & 15);
#pragma unroll
            for (int j = 0; j < 4; ++j)
                dst[(size_t)(row0 + j)*HID + col] = acc[m][n][j];
        }
    }
}

// ---- split-K reduce + bias; writes bf16 (fc6) or f32 (fc7) ----
__global__ void __launch_bounds__(256) k_reduce(const float* __restrict__ part,
                                                const float* __restrict__ bias,
                                                bf16_t* __restrict__ ob, float* __restrict__ of,
                                                int ksplit) {
    size_t idx = ((size_t)blockIdx.x*256 + threadIdx.x) * 4;
    f32x4 s = *reinterpret_cast<const f32x4*>(part + idx);
    for (int ss = 1; ss < ksplit; ++ss)
        s += *reinterpret_cast<const f32x4*>(part + (size_t)ss*MP*HID + idx);
    int col = (int)(idx & (HID - 1));
    s += *reinterpret_cast<const f32x4*>(bias + col);
    if (ob) {
#pragma unroll
        for (int j = 0; j < 4; ++j) ob[idx + j] = f2bf(s[j]);
    } else {
        *reinterpret_cast<f32x4*>(of + idx) = s;
    }
}

// ---- tiled column-dots: partial[kb][r][o] = fc7[r][kchunk] . Brow_o[kchunk] ----
// Brow_o = Bmat[o] (heads: W8T, 40 rows) or fc7[bidx[o]] (dmat gather).
// SELF adds output NOUT = ||fc7[r][kchunk]||^2 (for An).
template<int NOUT, bool SELF>
__global__ void __launch_bounds__(256) k_dotcols(const float* __restrict__ fc7,
        const float* __restrict__ Bmat, const int* __restrict__ bidx,
        float* __restrict__ partial) {
    constexpr int NO = NOUT + (SELF ? 1 : 0);
    constexpr int SLICE = NOUT*16 + 4;       // word stride per kk-slice: = 4 mod 32 -> 8 bank-quads
    __shared__ float Bs[8 * SLICE];
    const int rb = blockIdx.x, kb = blockIdx.y, t = threadIdx.x;
    const int k0 = kb * 128;
    for (int i = t; i < NOUT*32; i += 256) {             // stage Bmat chunk (f32x4 units)
        int o = i >> 5, c = i & 31;                      // c = k/4 within chunk
        const float* src = bidx ? fc7 + (size_t)bidx[o]*HID : Bmat + (size_t)o*HID;
        f32x4 v = *reinterpret_cast<const f32x4*>(src + k0 + c*4);
        *reinterpret_cast<f32x4*>(&Bs[(c >> 2)*SLICE + o*16 + (c & 3)*4]) = v;
    }
    __syncthreads();
    const int lane = t & 63, w = t >> 6;
    const int ri = lane >> 3, kk = lane & 7;
    const int r0 = rb*64 + w*16 + ri*2;                  // two rows per lane
    f32x4 x0[4], x1[4];
    const float* f0 = fc7 + (size_t)r0*HID + k0 + kk*16;
#pragma unroll
    for (int j = 0; j < 4; ++j) {
        x0[j] = *reinterpret_cast<const f32x4*>(f0 + j*4);
        x1[j] = *reinterpret_cast<const f32x4*>(f0 + HID + j*4);
    }
    float acc0[NO], acc1[NO];
#pragma unroll
    for (int o = 0; o < NOUT; ++o) {
        f32x4 s0 = {}, s1 = {};
#pragma unroll
        for (int j = 0; j < 4; ++j) {
            f32x4 wv = *reinterpret_cast<const f32x4*>(&Bs[kk*SLICE + o*16 + j*4]);
            s0 += x0[j] * wv;
            s1 += x1[j] * wv;
        }
        acc0[o] = s0[0]+s0[1]+s0[2]+s0[3];
        acc1[o] = s1[0]+s1[1]+s1[2]+s1[3];
    }
    if (SELF) {
        f32x4 s0 = {}, s1 = {};
#pragma unroll
        for (int j = 0; j < 4; ++j) { s0 += x0[j]*x0[j]; s1 += x1[j]*x1[j]; }
        acc0[NO-1] = s0[0]+s0[1]+s0[2]+s0[3];
        acc1[NO-1] = s1[0]+s1[1]+s1[2]+s1[3];
    }
#pragma unroll
    for (int o = 0; o < NO; ++o) {
#pragma unroll
        for (int m = 1; m < 8; m <<= 1) {
            acc0[o] += __shfl_xor(acc0[o], m, 64);
            acc1[o] += __shfl_xor(acc1[o], m, 64);
        }
    }
    if (kk == 0) {
#pragma unroll
        for (int o = 0; o < NO; ++o) {
            partial[((size_t)kb*MP + r0    )*NO + o] = acc0[o];
            partial[((size_t)kb*MP + r0 + 1)*NO + o] = acc1[o];
        }
    }
}

// ---- heads reduce: sum 32 k-chunk partials, add bias, row softmax -> pc; ld; An ----
__global__ void __launch_bounds__(64) k_headred(const float* __restrict__ hpart,
        const float* __restrict__ b8c, const float* __restrict__ b8d,
        float* __restrict__ pc, float* __restrict__ ld, float* __restrict__ An) {
    int r = blockIdx.x, t = threadIdx.x;
    __shared__ float lcs[20];
    if (t < 41) {
        float s = 0.f;
        for (int kb = 0; kb < 32; ++kb) s += hpart[((size_t)kb*MP + r)*41 + t];
        if (t < 20)      lcs[t] = s + b8c[t];
        else if (t < 40) ld[r*K_ + (t-20)] = s + b8d[t-20];
        else             An[r] = s;
    }
    __syncthreads();
    if (t == 0) {
        float mx = lcs[0];
#pragma unroll
        for (int k = 1; k < 20; ++k) mx = fmaxf(mx, lcs[k]);
        float sum = 0.f, e[20];
#pragma unroll
        for (int k = 0; k < 20; ++k) { e[k] = expf(lcs[k] - mx); sum += e[k]; }
        float inv = 1.f / sum;
#pragma unroll
        for (int k = 0; k < 20; ++k) pc[r*K_ + k] = e[k] * inv;
    }
}

// ---- dmat reduce: D[r][k] = sum of 32 partials ----
__global__ void __launch_bounds__(64) k_dmatred(const float* __restrict__ dpart,
                                                float* __restrict__ D) {
    int r = blockIdx.x, t = threadIdx.x;
    if (t < 20) {
        float s = 0.f;
        for (int kb = 0; kb < 32; ++kb) s += dpart[((size_t)kb*MP + r)*20 + t];
        D[r*K_ + t] = s;
    }
}

// ---- per-class column softmax, scores, column sum, argmin (stable) ----
__global__ void __launch_bounds__(256) k_pd(const float* __restrict__ ld,
        const float* __restrict__ pc, float* __restrict__ scores,
        float* __restrict__ out_sum, int* __restrict__ h_idx) {
    int k = blockIdx.x, t = threadIdx.x;
    __shared__ float sh[4];
    float m = -3.402823466e38f;
    for (int r = t; r < R_; r += 256) m = fmaxf(m, ld[r*K_ + k]);
    for (int off = 1; off < 64; off <<= 1) m = fmaxf(m, __shfl_xor(m, off, 64));
    if ((t & 63) == 0) sh[t >> 6] = m;
    __syncthreads();
    m = fmaxf(fmaxf(sh[0], sh[1]), fmaxf(sh[2], sh[3]));
    __syncthreads();
    float s = 0.f;
    for (int r = t; r < R_; r += 256) s += expf(ld[r*K_ + k] - m);
    for (int off = 1; off < 64; off <<= 1) s += __shfl_xor(s, off, 64);
    if ((t & 63) == 0) sh[t >> 6] = s;
    __syncthreads();
    s = sh[0] + sh[1] + sh[2] + sh[3];
    float inv = 1.f / s;

    float osum = 0.f, bv = 3.402823466e38f; int bi = 0x7fffffff;
    for (int r = t; r < R_; r += 256) {
        float p  = expf(ld[r*K_ + k] - m) * inv;
        float sc = pc[r*K_ + k] * p;
        scores[r*K_ + k] = sc;
        osum += sc;
        if (sc < bv || (sc == bv && r < bi)) { bv = sc; bi = r; }
    }
    for (int off = 1; off < 64; off <<= 1) osum += __shfl_xor(osum, off, 64);
    for (int off = 1; off < 64; off <<= 1) {
        float v2 = __shfl_xor(bv, off, 64);
        int   i2 = __shfl_xor(bi, off, 64);
        if (v2 < bv || (v2 == bv && i2 < bi)) { bv = v2; bi = i2; }
    }
    __shared__ float so[4], mv[4]; __shared__ int mi[4];
    if ((t & 63) == 0) { so[t >> 6] = osum; mv[t >> 6] = bv; mi[t >> 6] = bi; }
    __syncthreads();
    if (t == 0) {
        out_sum[k] = so[0] + so[1] + so[2] + so[3];
        float v = mv[0]; int i = mi[0];
        for (int w = 1; w < 4; ++w)
            if (mv[w] < v || (mv[w] == v && mi[w] < i)) { v = mv[w]; i = mi[w]; }
        h_idx[k] = i;
    }
}

// ---- final: BCE + spatial regularizer ----
__global__ void __launch_bounds__(256) k_final(const float* __restrict__ out_sum,
        const int* __restrict__ h_idx, const float* __restrict__ label,
        const float* __restrict__ scores, const float* __restrict__ D,
        const float* __restrict__ An, const float* __restrict__ rois_sc,
        float* __restrict__ dout) {
    int t = threadIdx.x;
    __shared__ float bsh[20];
    if (t < 20) {
        float o = out_sum[t], lab = label[t];
        bsh[t] = lab * logf(o) + (1.f - lab) * logf(1.f - o);
    }
    __syncthreads();

    float rp = 0.f;
    for (int i = t; i < R_*K_; i += 256) {
        int r = i / 20, k = i - r*20;
        int h = h_idx[k];
        if (r == h) continue;
        float lab = label[k];
        if (lab == 0.f) continue;
        float s = scores[r*K_ + k];
        const float* rb = rois_sc + r*4;
        const float* hb = rois_sc + h*4;
        float b1x2 = rb[0] + rb[2], b1y2 = rb[1] + rb[3];
        float b2x2 = hb[0] + hb[2], b2y2 = hb[1] + hb[3];
        float iw = fmaxf(fminf(b1x2, b2x2) - fmaxf(rb[0], hb[0]) + 1.f, 0.f);
        float ih = fmaxf(fminf(b1y2, b2y2) - fmaxf(rb[1], hb[1]) + 1.f, 0.f);
        float inter = iw * ih;
        float a1 = (b1x2 - rb[0] + 1.f) * (b1y2 - rb[1] + 1.f);
        float a2 = (b2x2 - hb[0] + 1.f) * (b2y2 - hb[1] + 1.f);
        float iou = inter / (a1 + a2 - inter);
        float mm = (iou > 0.6f) ? 1.f : 0.f;
        float term = mm * (An[r] - 2.f * D[r*K_ + k]) + An[h];
        rp += lab * 0.5f * s * s * term;
    }
    for (int off = 1; off < 64; off <<= 1) rp += __shfl_xor(rp, off, 64);
    __shared__ float rsh[4];
    if ((t & 63) == 0) rsh[t >> 6] = rp;
    __syncthreads();
    if (t == 0) {
        float reg = (rsh[0] + rsh[1] + rsh[2] + rsh[3]) / (float)K_;
        float b = 0.f;
        for (int k = 0; k < 20; ++k) b += bsh[k];
        float bce = -b / (float)K_;
        dout[R_*K_]     = bce + reg;
        dout[R_*K_ + 1] = reg;
    }
}

extern "C" void kernel_launch(void* const* d_in, const int* in_sizes, int n_in,
                              void* d_out, int out_size, void* d_ws, size_t ws_size,
                              hipStream_t stream) {
    const float* fmap  = (const float*)d_in[0];
    const float* rois  = (const float*)d_in[1];
    const float* label = (const float*)d_in[2];
    const float* W6    = (const float*)d_in[3];
    const float* b6    = (const float*)d_in[4];
    const float* W7    = (const float*)d_in[5];
    const float* b7    = (const float*)d_in[6];
    const float* W8c   = (const float*)d_in[7];
    const float* b8c   = (const float*)d_in[8];
    const float* W8d   = (const float*)d_in[9];
    const float* b8d   = (const float*)d_in[10];
    char* ws = (char*)d_ws;
    float* out = (float*)d_out;

    float*  fmapt = (float*)(ws + O_FMT);
    float*  roisc = (float*)(ws + O_RSC);
    bf16_t* feat  = (bf16_t*)(ws + O_FEAT);
    bf16_t* fc6   = (bf16_t*)(ws + O_FC6);
    float*  fc7   = (float*)(ws + O_FC7);
    float*  pc    = (float*)(ws + O_PC);
    float*  ld    = (float*)(ws + O_LD);
    float*  An    = (float*)(ws + O_AN);
    float*  osum  = (float*)(ws + O_OS);
    int*    hidx  = (int*)(ws + O_HI);
    float*  Dm    = (float*)(ws + O_D);
    float*  w8t   = (float*)(ws + O_W8T);
    float*  part  = (float*)(ws + O_PART);
    float*  hpart = (float*)(ws + O_HP);
    float*  dpart = (float*)(ws + O_DP);

    const int ksplit = 4;

    k_transpose<<<dim3((HW + 31)/32, C_/32), dim3(256), 0, stream>>>(fmap, fmapt);
    k_w8t      <<<dim3(2*K_),   dim3(256), 0, stream>>>(W8c, W8d, w8t);
    k_roipool  <<<dim3(MP, 9),  dim3(256), 0, stream>>>(fmapt, rois, feat, roisc);

    k_gemm  <<<dim3(HID/128, MP/128, ksplit), dim3(256), 0, stream>>>(feat, W6, part, FEAT, (FEAT/64)/ksplit);
    k_reduce<<<dim3((MP*HID)/1024), dim3(256), 0, stream>>>(part, b6, fc6, (float*)nullptr, ksplit);

    k_gemm  <<<dim3(HID/128, MP/128, ksplit), dim3(256), 0, stream>>>(fc6, W7, part, HID, (HID/64)/ksplit);
    k_reduce<<<dim3((MP*HID)/1024), dim3(256), 0, stream>>>(part, b7, (bf16_t*)nullptr, fc7, ksplit);

    k_dotcols<40, true><<<dim3(MP/64, HID/128), dim3(256), 0, stream>>>(fc7, w8t, (const int*)nullptr, hpart);
    k_headred<<<dim3(R_), dim3(64), 0, stream>>>(hpart, b8c, b8d, pc, ld, An);
    k_pd     <<<dim3(K_), dim3(256), 0, stream>>>(ld, pc, out, osum, hidx);
    k_dotcols<20, false><<<dim3(MP/64, HID/128), dim3(256), 0, stream>>>(fc7, (const float*)nullptr, hidx, dpart);
    k_dmatred<<<dim3(R_), dim3(64), 0, stream>>>(dpart, Dm);
    k_final  <<<dim3(1),  dim3(256), 0, stream>>>(osum, hidx, label, out, Dm, An, roisc, out);
}

// Round 7
// 177.344 us; speedup vs baseline: 1.1228x; 1.0067x over previous
//
#include <hip/hip_runtime.h>
#include <cstdint>
#include <cstddef>

#define DEV __device__ __forceinline__

typedef __bf16 bf16_t;
typedef __bf16 bf16x8 __attribute__((ext_vector_type(8)));
typedef float  f32x4  __attribute__((ext_vector_type(4)));
typedef float  f32x2  __attribute__((ext_vector_type(2)));
typedef unsigned int u32x4 __attribute__((ext_vector_type(4)));

DEV bf16_t f2bf(float x) { return (bf16_t)x; }   // RNE cast

// ---- problem sizes ----
constexpr int R_ = 500, C_ = 512, H_ = 38, W_ = 38, K_ = 20;
constexpr int HID = 4096, FEAT = 4608, MP = 512;  // MP = padded M
constexpr int HW = H_ * W_;                        // 1444

// ---- workspace layout ----
constexpr size_t alup(size_t x) { return (x + 255) & ~(size_t)255; }
constexpr size_t O_FMT  = 0;                                        // fmap transposed [1444][512] f32
constexpr size_t O_RSC  = alup(O_FMT  + (size_t)HW*C_*4);           // rois_sc [500][4] f32
constexpr size_t O_FEAT = alup(O_RSC  + (size_t)R_*4*4);            // feat bf16 [512][4608]
constexpr size_t O_FC6  = alup(O_FEAT + (size_t)MP*FEAT*2);         // fc6 bf16 [512][4096]
constexpr size_t O_FC7  = alup(O_FC6  + (size_t)MP*HID*2);          // fc7 f32 [512][4096]
constexpr size_t O_PC   = alup(O_FC7  + (size_t)MP*HID*4);          // pc [500][20] f32
constexpr size_t O_LD   = alup(O_PC   + (size_t)R_*K_*4);           // logits_d [500][20] f32
constexpr size_t O_AN   = alup(O_LD   + (size_t)R_*K_*4);           // ||fc7[r]||^2 [512] f32
constexpr size_t O_OS   = alup(O_AN   + (size_t)MP*4);              // out_sum [20]
constexpr size_t O_HI   = alup(O_OS   + (size_t)K_*4);              // h_idx [20] int
constexpr size_t O_D    = alup(O_HI   + (size_t)K_*4);              // D [500][20] f32
constexpr size_t O_W8T  = alup(O_D    + (size_t)R_*K_*4);           // W8T [40][4096] f32
constexpr size_t O_PART = alup(O_W8T  + (size_t)2*K_*HID*4);        // split-K partials (33.5 MB)
// heads/dmat partials alias the part region (part is dead by then)
constexpr size_t O_HP   = O_PART;                                   // [32][512][41] f32 (2.75 MB)
constexpr size_t O_DP   = O_PART + (size_t)4*1024*1024;             // [32][512][20] f32 (1.31 MB)

// ---- fmap transpose: [C][HW] -> [HW][C], tiled through LDS (both sides coalesced) ----
__global__ void __launch_bounds__(256) k_transpose(const float* __restrict__ fmap,
                                                   float* __restrict__ fmapt) {
    __shared__ float tile[32][33];
    int p0 = blockIdx.x * 32, c0 = blockIdx.y * 32;
    int tx = threadIdx.x & 31, ty = threadIdx.x >> 5;     // ty in 0..7
#pragma unroll
    for (int i = 0; i < 4; ++i) {
        int c = c0 + ty + i*8, p = p0 + tx;
        tile[ty + i*8][tx] = (p < HW) ? fmap[(size_t)c*HW + p] : 0.f;
    }
    __syncthreads();
#pragma unroll
    for (int i = 0; i < 4; ++i) {
        int p = p0 + ty + i*8, c = c0 + tx;
        if (p < HW) fmapt[(size_t)p*C_ + c] = tile[tx][ty + i*8];
    }
}

// ---- W8c/W8d transpose: [4096][20] -> W8T[40][4096] ----
__global__ void __launch_bounds__(256) k_w8t(const float* __restrict__ W8c,
                                             const float* __restrict__ W8d,
                                             float* __restrict__ W8T) {
    int k = blockIdx.x;                                   // 0..39
    const float* src = (k < K_) ? W8c : W8d;
    int kk = (k < K_) ? k : k - K_;
    for (int i = threadIdx.x; i < HID; i += 256)
        W8T[(size_t)k*HID + i] = src[(size_t)i*K_ + kk];
}

// ---- ROI max pool, split over (roi, bin): feat[r, c*9 + bin] ----
__global__ void __launch_bounds__(256) k_roipool(const float* __restrict__ fmapt,
                                                 const float* __restrict__ rois,
                                                 bf16_t* __restrict__ feat,
                                                 float* __restrict__ rois_sc) {
    int r = blockIdx.x, bin = blockIdx.y, t = threadIdx.x;
    if (r >= R_) {   // zero the M-padding rows so the GEMM sees zeros
        feat[(size_t)r*FEAT + (size_t)t*9       + bin] = (bf16_t)0.f;
        feat[(size_t)r*FEAT + (size_t)(t+256)*9 + bin] = (bf16_t)0.f;
        return;
    }
    int x1 = (int)floorf(rois[r*4+0] * 0.0625f);
    int y1 = (int)floorf(rois[r*4+1] * 0.0625f);
    int x2 = (int)floorf(rois[r*4+2] * 0.0625f);
    int y2 = (int)floorf(rois[r*4+3] * 0.0625f);
    if (bin == 0 && t == 0) {
        rois_sc[r*4+0] = (float)x1; rois_sc[r*4+1] = (float)y1;
        rois_sc[r*4+2] = (float)x2; rois_sc[r*4+3] = (float)y2;
    }
    int Lx = x2 - x1, Ly = y2 - y1;
    int pr = bin / 3, px = bin - pr*3;
    int rs = y1 + (pr*Ly)/3, re = y1 + ((pr+1)*Ly + 2)/3;
    int cs = x1 + (px*Lx)/3, ce = x1 + ((px+1)*Lx + 2)/3;
    float m0 = -3.402823466e38f, m1 = -3.402823466e38f;
    for (int y = rs; y < re; ++y) {
        const float* rowp = fmapt + (size_t)(y*W_)*C_;
        for (int x = cs; x < ce; ++x) {
            const float* p = rowp + (size_t)x*C_;
            m0 = fmaxf(m0, p[t]);
            m1 = fmaxf(m1, p[t + 256]);
        }
    }
    feat[(size_t)r*FEAT + (size_t)t*9       + bin] = f2bf(m0);
    feat[(size_t)r*FEAT + (size_t)(t+256)*9 + bin] = f2bf(m1);
}

// ---- bf16 MFMA GEMM: part[bz] = A[512xK](bf16) * B[Kx4096](f32 -> bf16) ----
// BM=BN=128, BK=64, 4 waves (64x64 each). Depth-2 software pipeline:
//   A: triple-buffered LDS, global_load_lds issued 2 iterations ahead
//   B: loads for t+2 issued at top of iter t into alternating reg sets;
//      write_B(t+1) after compute(t) -- the only forced wait is the
//      compiler's COUNTED vmcnt for 1-iteration-old B regs (12 newer ops
//      stay in flight). Raw s_barrier (no vmcnt(0) drain) + lgkmcnt(0).
// XOR-swizzled LDS (r4-verified: 0 bank conflicts). 80 KB -> 2 blocks/CU.
__global__ void __launch_bounds__(256, 2)
k_gemm(const bf16_t* __restrict__ A, const float* __restrict__ B,
       float* __restrict__ part, int KDIM, int nts) {
    __shared__ bf16_t Asm[3][128*64];   // 16 KB each (triple)
    __shared__ bf16_t Bsm[2][128*64];   // 16 KB each, [n][k] swizzled (double)
    const int t = threadIdx.x;
    const int lane = t & 63, wid = t >> 6;
    const int wr = wid >> 1, wc = wid & 1;

    // XCD-aware bijective decode: grid (32,4,4); by fastest within a chunk so
    // the 4 M-tiles sharing a B panel are temporally adjacent on one XCD.
    const int flat = blockIdx.x + 32*blockIdx.y + 128*blockIdx.z;
    const int q = 16 * gridDim.z;                       // nwg/8
    const int v = (flat & 7) * q + (flat >> 3);
    const int by = v & 3, bx = (v >> 2) & 31, bz = v >> 7;

    const int brow = by * 128, bcol = bx * 128;
    const int kt0 = bz * nts;

    f32x4 acc[4][4] = {};
    const int n2 = t & 63, kgl = t >> 6;      // B: cols {2n2,2n2+1}, k-stripe kgl*16

    auto stage_A = [&](int kt, bf16_t* dstbuf) {   // async global->LDS, swizzled src
        const bf16_t* Ag = A + (size_t)brow*KDIM + kt*64;
#pragma unroll
        for (int i = 0; i < 4; ++i) {
            int s = t + i*256;                          // LDS 16B-slot (linear dest)
            int row = s >> 3;
            int kb = (s & 7) ^ ((row >> 1) & 7);        // pre-swizzled source octet
            const bf16_t* src = Ag + (size_t)row*KDIM + kb*8;
            bf16_t* dst = dstbuf + (size_t)(i*256 + (t & ~63)) * 8;  // wave-uniform base
            __builtin_amdgcn_global_load_lds(
                (const __attribute__((address_space(1))) void*)src,
                (__attribute__((address_space(3))) void*)dst, 16, 0, 0);
        }
    };
    auto load_B = [&](int kt, f32x2* br) {
        const float* src = B + (size_t)(kt*64 + kgl*16)*HID + bcol + 2*n2;
#pragma unroll
        for (int j = 0; j < 16; ++j)                    // wave-coalesced 512B rows
            br[j] = *reinterpret_cast<const f32x2*>(src + (size_t)j*HID);
    };
    auto write_B = [&](f32x2* br, bf16_t* buf) {
        const int sw = n2 & 7;                          // (col>>1)&7, same for both cols
        bf16x8 v0, v1;
#pragma unroll
        for (int j = 0; j < 8; ++j) { v0[j] = f2bf(br[j].x); v1[j] = f2bf(br[j+8].x); }
        *reinterpret_cast<u32x4*>(&buf[(size_t)((2*n2)*8 + ((kgl*2    ) ^ sw)) * 8]) = *reinterpret_cast<u32x4*>(&v0);
        *reinterpret_cast<u32x4*>(&buf[(size_t)((2*n2)*8 + ((kgl*2 + 1) ^ sw)) * 8]) = *reinterpret_cast<u32x4*>(&v1);
#pragma unroll
        for (int j = 0; j < 8; ++j) { v0[j] = f2bf(br[j].y); v1[j] = f2bf(br[j+8].y); }
        *reinterpret_cast<u32x4*>(&buf[(size_t)((2*n2+1)*8 + ((kgl*2    ) ^ sw)) * 8]) = *reinterpret_cast<u32x4*>(&v0);
        *reinterpret_cast<u32x4*>(&buf[(size_t)((2*n2+1)*8 + ((kgl*2 + 1) ^ sw)) * 8]) = *reinterpret_cast<u32x4*>(&v1);
    };

    bf16_t* pa0 = &Asm[0][0]; bf16_t* pa1 = &Asm[1][0]; bf16_t* pa2 = &Asm[2][0];
    bf16_t* pb0 = &Bsm[0][0]; bf16_t* pb1 = &Bsm[1][0];
    f32x2 brA[16], brB[16];

    // prologue: stage A(0),A(1); load B(0),B(1); commit B(0) to LDS
    stage_A(kt0 + 0, pa0);
    load_B (kt0 + 0, brA);
    stage_A(kt0 + 1, pa1);
    load_B (kt0 + 1, brB);
    write_B(brA, pb0);                 // compiler inserts counted vmcnt for brA
    asm volatile("s_waitcnt lgkmcnt(0)" ::: "memory");
    __builtin_amdgcn_s_barrier();
    __builtin_amdgcn_sched_barrier(0);

    auto body = [&](int tt, f32x2* prev, f32x2* next) {
        if (tt + 2 < nts) { stage_A(kt0 + tt + 2, pa2); load_B(kt0 + tt + 2, next); }
#pragma unroll
        for (int kk = 0; kk < 2; ++kk) {
            const int kb = kk*4 + (lane >> 4);
            bf16x8 af[4], bfr[4];
#pragma unroll
            for (int m = 0; m < 4; ++m) {
                int row = wr*64 + m*16 + (lane & 15);
                af[m] = *reinterpret_cast<const bf16x8*>(
                    pa0 + (size_t)(row*8 + (kb ^ ((row >> 1) & 7))) * 8);
            }
#pragma unroll
            for (int n = 0; n < 4; ++n) {
                int nn = wc*64 + n*16 + (lane & 15);
                bfr[n] = *reinterpret_cast<const bf16x8*>(
                    pb0 + (size_t)(nn*8 + (kb ^ ((nn >> 1) & 7))) * 8);
            }
#pragma unroll
            for (int m = 0; m < 4; ++m)
#pragma unroll
                for (int n = 0; n < 4; ++n)
                    acc[m][n] = __builtin_amdgcn_mfma_f32_16x16x32_bf16(af[m], bfr[n], acc[m][n], 0, 0, 0);
        }
        if (tt + 1 < nts) {
            write_B(prev, pb1);        // B(t+1) into the other buffer; counted vmcnt
            asm volatile("s_waitcnt lgkmcnt(0)" ::: "memory");
            __builtin_amdgcn_s_barrier();
            __builtin_amdgcn_sched_barrier(0);
        }
        bf16_t* ta = pa0; pa0 = pa1; pa1 = pa2; pa2 = ta;   // rotate A triple-buffer
        bf16_t* tb = pb0; pb0 = pb1; pb1 = tb;              // swap B double-buffer
    };

    for (int it = 0; it < nts; it += 2) {      // nts is even (18 or 16)
        body(it,     brB, brA);                // prev holds B(it+1)
        body(it + 1, brA, brB);
    }

    float* dst = part + (size_t)bz * MP * HID;
#pragma unroll
    for (int m = 0; m < 4; ++m) {
        int row0 = brow + wr*64 + m*16 + ((lane >> 4) << 2);
#pragma unroll
        for (int n = 0; n < 4; ++n) {
            int col = bcol + wc*64 + n*16 + (lane & 15);
#pragma unroll
            for (int j = 0; j < 4; ++j)
                dst[(size_t)(row0 + j)*HID + col] = acc[m][n][j];
        }
    }
}

// ---- split-K reduce + bias; writes bf16 (fc6) or f32 (fc7) ----
__global__ void __launch_bounds__(256) k_reduce(const float* __restrict__ part,
                                                const float* __restrict__ bias,
                                                bf16_t* __restrict__ ob, float* __restrict__ of,
                                                int ksplit) {
    size_t idx = ((size_t)blockIdx.x*256 + threadIdx.x) * 4;
    f32x4 s = *reinterpret_cast<const f32x4*>(part + idx);
    for (int ss = 1; ss < ksplit; ++ss)
        s += *reinterpret_cast<const f32x4*>(part + (size_t)ss*MP*HID + idx);
    int col = (int)(idx & (HID - 1));
    s += *reinterpret_cast<const f32x4*>(bias + col);
    if (ob) {
#pragma unroll
        for (int j = 0; j < 4; ++j) ob[idx + j] = f2bf(s[j]);
    } else {
        *reinterpret_cast<f32x4*>(of + idx) = s;
    }
}

// ---- tiled column-dots: partial[kb][r][o] = fc7[r][kchunk] . Brow_o[kchunk] ----
// Brow_o = Bmat[o] (heads: W8T, 40 rows) or fc7[bidx[o]] (dmat gather).
// SELF adds output NOUT = ||fc7[r][kchunk]||^2 (for An).
template<int NOUT, bool SELF>
__global__ void __launch_bounds__(256) k_dotcols(const float* __restrict__ fc7,
        const float* __restrict__ Bmat, const int* __restrict__ bidx,
        float* __restrict__ partial) {
    constexpr int NO = NOUT + (SELF ? 1 : 0);
    constexpr int SLICE = NOUT*16 + 4;       // word stride per kk-slice: = 4 mod 32 -> 8 bank-quads
    __shared__ float Bs[8 * SLICE];
    const int rb = blockIdx.x, kb = blockIdx.y, t = threadIdx.x;
    const int k0 = kb * 128;
    for (int i = t; i < NOUT*32; i += 256) {             // stage Bmat chunk (f32x4 units)
        int o = i >> 5, c = i & 31;                      // c = k/4 within chunk
        const float* src = bidx ? fc7 + (size_t)bidx[o]*HID : Bmat + (size_t)o*HID;
        f32x4 v = *reinterpret_cast<const f32x4*>(src + k0 + c*4);
        *reinterpret_cast<f32x4*>(&Bs[(c >> 2)*SLICE + o*16 + (c & 3)*4]) = v;
    }
    __syncthreads();
    const int lane = t & 63, w = t >> 6;
    const int ri = lane >> 3, kk = lane & 7;
    const int r0 = rb*64 + w*16 + ri*2;                  // two rows per lane
    f32x4 x0[4], x1[4];
    const float* f0 = fc7 + (size_t)r0*HID + k0 + kk*16;
#pragma unroll
    for (int j = 0; j < 4; ++j) {
        x0[j] = *reinterpret_cast<const f32x4*>(f0 + j*4);
        x1[j] = *reinterpret_cast<const f32x4*>(f0 + HID + j*4);
    }
    float acc0[NO], acc1[NO];
#pragma unroll
    for (int o = 0; o < NOUT; ++o) {
        f32x4 s0 = {}, s1 = {};
#pragma unroll
        for (int j = 0; j < 4; ++j) {
            f32x4 wv = *reinterpret_cast<const f32x4*>(&Bs[kk*SLICE + o*16 + j*4]);
            s0 += x0[j] * wv;
            s1 += x1[j] * wv;
        }
        acc0[o] = s0[0]+s0[1]+s0[2]+s0[3];
        acc1[o] = s1[0]+s1[1]+s1[2]+s1[3];
    }
    if (SELF) {
        f32x4 s0 = {}, s1 = {};
#pragma unroll
        for (int j = 0; j < 4; ++j) { s0 += x0[j]*x0[j]; s1 += x1[j]*x1[j]; }
        acc0[NO-1] = s0[0]+s0[1]+s0[2]+s0[3];
        acc1[NO-1] = s1[0]+s1[1]+s1[2]+s1[3];
    }
#pragma unroll
    for (int o = 0; o < NO; ++o) {
#pragma unroll
        for (int m = 1; m < 8; m <<= 1) {
            acc0[o] += __shfl_xor(acc0[o], m, 64);
            acc1[o] += __shfl_xor(acc1[o], m, 64);
        }
    }
    if (kk == 0) {
#pragma unroll
        for (int o = 0; o < NO; ++o) {
            partial[((size_t)kb*MP + r0    )*NO + o] = acc0[o];
            partial[((size_t)kb*MP + r0 + 1)*NO + o] = acc1[o];
        }
    }
}

// ---- heads reduce: sum 32 k-chunk partials, add bias, row softmax -> pc; ld; An ----
__global__ void __launch_bounds__(64) k_headred(const float* __restrict__ hpart,
        const float* __restrict__ b8c, const float* __restrict__ b8d,
        float* __restrict__ pc, float* __restrict__ ld, float* __restrict__ An) {
    int r = blockIdx.x, t = threadIdx.x;
    __shared__ float lcs[20];
    if (t < 41) {
        float s = 0.f;
        for (int kb = 0; kb < 32; ++kb) s += hpart[((size_t)kb*MP + r)*41 + t];
        if (t < 20)      lcs[t] = s + b8c[t];
        else if (t < 40) ld[r*K_ + (t-20)] = s + b8d[t-20];
        else             An[r] = s;
    }
    __syncthreads();
    if (t == 0) {
        float mx = lcs[0];
#pragma unroll
        for (int k = 1; k < 20; ++k) mx = fmaxf(mx, lcs[k]);
        float sum = 0.f, e[20];
#pragma unroll
        for (int k = 0; k < 20; ++k) { e[k] = expf(lcs[k] - mx); sum += e[k]; }
        float inv = 1.f / sum;
#pragma unroll
        for (int k = 0; k < 20; ++k) pc[r*K_ + k] = e[k] * inv;
    }
}

// ---- dmat reduce: D[r][k] = sum of 32 partials ----
__global__ void __launch_bounds__(64) k_dmatred(const float* __restrict__ dpart,
                                                float* __restrict__ D) {
    int r = blockIdx.x, t = threadIdx.x;
    if (t < 20) {
        float s = 0.f;
        for (int kb = 0; kb < 32; ++kb) s += dpart[((size_t)kb*MP + r)*20 + t];
        D[r*K_ + t] = s;
    }
}

// ---- per-class column softmax, scores, column sum, argmin (stable) ----
__global__ void __launch_bounds__(256) k_pd(const float* __restrict__ ld,
        const float* __restrict__ pc, float* __restrict__ scores,
        float* __restrict__ out_sum, int* __restrict__ h_idx) {
    int k = blockIdx.x, t = threadIdx.x;
    __shared__ float sh[4];
    float m = -3.402823466e38f;
    for (int r = t; r < R_; r += 256) m = fmaxf(m, ld[r*K_ + k]);
    for (int off = 1; off < 64; off <<= 1) m = fmaxf(m, __shfl_xor(m, off, 64));
    if ((t & 63) == 0) sh[t >> 6] = m;
    __syncthreads();
    m = fmaxf(fmaxf(sh[0], sh[1]), fmaxf(sh[2], sh[3]));
    __syncthreads();
    float s = 0.f;
    for (int r = t; r < R_; r += 256) s += expf(ld[r*K_ + k] - m);
    for (int off = 1; off < 64; off <<= 1) s += __shfl_xor(s, off, 64);
    if ((t & 63) == 0) sh[t >> 6] = s;
    __syncthreads();
    s = sh[0] + sh[1] + sh[2] + sh[3];
    float inv = 1.f / s;

    float osum = 0.f, bv = 3.402823466e38f; int bi = 0x7fffffff;
    for (int r = t; r < R_; r += 256) {
        float p  = expf(ld[r*K_ + k] - m) * inv;
        float sc = pc[r*K_ + k] * p;
        scores[r*K_ + k] = sc;
        osum += sc;
        if (sc < bv || (sc == bv && r < bi)) { bv = sc; bi = r; }
    }
    for (int off = 1; off < 64; off <<= 1) osum += __shfl_xor(osum, off, 64);
    for (int off = 1; off < 64; off <<= 1) {
        float v2 = __shfl_xor(bv, off, 64);
        int   i2 = __shfl_xor(bi, off, 64);
        if (v2 < bv || (v2 == bv && i2 < bi)) { bv = v2; bi = i2; }
    }
    __shared__ float so[4], mv[4]; __shared__ int mi[4];
    if ((t & 63) == 0) { so[t >> 6] = osum; mv[t >> 6] = bv; mi[t >> 6] = bi; }
    __syncthreads();
    if (t == 0) {
        out_sum[k] = so[0] + so[1] + so[2] + so[3];
        float v = mv[0]; int i = mi[0];
        for (int w = 1; w < 4; ++w)
            if (mv[w] < v || (mv[w] == v && mi[w] < i)) { v = mv[w]; i = mi[w]; }
        h_idx[k] = i;
    }
}

// ---- final: BCE + spatial regularizer ----
__global__ void __launch_bounds__(256) k_final(const float* __restrict__ out_sum,
        const int* __restrict__ h_idx, const float* __restrict__ label,
        const float* __restrict__ scores, const float* __restrict__ D,
        const float* __restrict__ An, const float* __restrict__ rois_sc,
        float* __restrict__ dout) {
    int t = threadIdx.x;
    __shared__ float bsh[20];
    if (t < 20) {
        float o = out_sum[t], lab = label[t];
        bsh[t] = lab * logf(o) + (1.f - lab) * logf(1.f - o);
    }
    __syncthreads();

    float rp = 0.f;
    for (int i = t; i < R_*K_; i += 256) {
        int r = i / 20, k = i - r*20;
        int h = h_idx[k];
        if (r == h) continue;
        float lab = label[k];
        if (lab == 0.f) continue;
        float s = scores[r*K_ + k];
        const float* rb = rois_sc + r*4;
        const float* hb = rois_sc + h*4;
        float b1x2 = rb[0] + rb[2], b1y2 = rb[1] + rb[3];
        float b2x2 = hb[0] + hb[2], b2y2 = hb[1] + hb[3];
        float iw = fmaxf(fminf(b1x2, b2x2) - fmaxf(rb[0], hb[0]) + 1.f, 0.f);
        float ih = fmaxf(fminf(b1y2, b2y2) - fmaxf(rb[1], hb[1]) + 1.f, 0.f);
        float inter = iw * ih;
        float a1 = (b1x2 - rb[0] + 1.f) * (b1y2 - rb[1] + 1.f);
        float a2 = (b2x2 - hb[0] + 1.f) * (b2y2 - hb[1] + 1.f);
        float iou = inter / (a1 + a2 - inter);
        float mm = (iou > 0.6f) ? 1.f : 0.f;
        float term = mm * (An[r] - 2.f * D[r*K_ + k]) + An[h];
        rp += lab * 0.5f * s * s * term;
    }
    for (int off = 1; off < 64; off <<= 1) rp += __shfl_xor(rp, off, 64);
    __shared__ float rsh[4];
    if ((t & 63) == 0) rsh[t >> 6] = rp;
    __syncthreads();
    if (t == 0) {
        float reg = (rsh[0] + rsh[1] + rsh[2] + rsh[3]) / (float)K_;
        float b = 0.f;
        for (int k = 0; k < 20; ++k) b += bsh[k];
        float bce = -b / (float)K_;
        dout[R_*K_]     = bce + reg;
        dout[R_*K_ + 1] = reg;
    }
}

extern "C" void kernel_launch(void* const* d_in, const int* in_sizes, int n_in,
                              void* d_out, int out_size, void* d_ws, size_t ws_size,
                              hipStream_t stream) {
    const float* fmap  = (const float*)d_in[0];
    const float* rois  = (const float*)d_in[1];
    const float* label = (const float*)d_in[2];
    const float* W6    = (const float*)d_in[3];
    const float* b6    = (const float*)d_in[4];
    const float* W7    = (const float*)d_in[5];
    const float* b7    = (const float*)d_in[6];
    const float* W8c   = (const float*)d_in[7];
    const float* b8c   = (const float*)d_in[8];
    const float* W8d   = (const float*)d_in[9];
    const float* b8d   = (const float*)d_in[10];
    char* ws = (char*)d_ws;
    float* out = (float*)d_out;

    float*  fmapt = (float*)(ws + O_FMT);
    float*  roisc = (float*)(ws + O_RSC);
    bf16_t* feat  = (bf16_t*)(ws + O_FEAT);
    bf16_t* fc6   = (bf16_t*)(ws + O_FC6);
    float*  fc7   = (float*)(ws + O_FC7);
    float*  pc    = (float*)(ws + O_PC);
    float*  ld    = (float*)(ws + O_LD);
    float*  An    = (float*)(ws + O_AN);
    float*  osum  = (float*)(ws + O_OS);
    int*    hidx  = (int*)(ws + O_HI);
    float*  Dm    = (float*)(ws + O_D);
    float*  w8t   = (float*)(ws + O_W8T);
    float*  part  = (float*)(ws + O_PART);
    float*  hpart = (float*)(ws + O_HP);
    float*  dpart = (float*)(ws + O_DP);

    const int ksplit = 4;

    k_transpose<<<dim3((HW + 31)/32, C_/32), dim3(256), 0, stream>>>(fmap, fmapt);
    k_w8t      <<<dim3(2*K_),   dim3(256), 0, stream>>>(W8c, W8d, w8t);
    k_roipool  <<<dim3(MP, 9),  dim3(256), 0, stream>>>(fmapt, rois, feat, roisc);

    k_gemm  <<<dim3(HID/128, MP/128, ksplit), dim3(256), 0, stream>>>(feat, W6, part, FEAT, (FEAT/64)/ksplit);
    k_reduce<<<dim3((MP*HID)/1024), dim3(256), 0, stream>>>(part, b6, fc6, (float*)nullptr, ksplit);

    k_gemm  <<<dim3(HID/128, MP/128, ksplit), dim3(256), 0, stream>>>(fc6, W7, part, HID, (HID/64)/ksplit);
    k_reduce<<<dim3((MP*HID)/1024), dim3(256), 0, stream>>>(part, b7, (bf16_t*)nullptr, fc7, ksplit);

    k_dotcols<40, true><<<dim3(MP/64, HID/128), dim3(256), 0, stream>>>(fc7, w8t, (const int*)nullptr, hpart);
    k_headred<<<dim3(R_), dim3(64), 0, stream>>>(hpart, b8c, b8d, pc, ld, An);
    k_pd     <<<dim3(K_), dim3(256), 0, stream>>>(ld, pc, out, osum, hidx);
    k_dotcols<20, false><<<dim3(MP/64, HID/128), dim3(256), 0, stream>>>(fc7, (const float*)nullptr, hidx, dpart);
    k_dmatred<<<dim3(R_), dim3(64), 0, stream>>>(dpart, Dm);
    k_final  <<<dim3(1),  dim3(256), 0, stream>>>(osum, hidx, label, out, Dm, An, roisc, out);
}